// Round 10
// baseline (326.047 us; speedup 1.0000x reference)
//
#include <hip/hip_runtime.h>
#include <math.h>

typedef unsigned short u16;
typedef unsigned int u32;
typedef unsigned long long u64;
typedef _Float16 f16;
typedef __attribute__((ext_vector_type(8))) _Float16 f16x8;
typedef __attribute__((ext_vector_type(4))) float f32x4;

#define L      1024
#define NH     8
#define DH     64
#define DR     32
#define KTS    96
#define LWIN   64
#define NKV    1024   // [kc 512 | vc 512]
#define NQP    768    // [qc 512 | qrp 256]

__device__ __forceinline__ float softplusf(float x) {
  return fmaxf(x, 0.f) + log1pf(expf(-fabsf(x)));
}
__device__ __forceinline__ f32x4 mf16(f16x8 a, f16x8 b, f32x4 c) {
  return __builtin_amdgcn_mfma_f32_16x16x32_f16(a, b, c, 0, 0, 0);
}
__device__ __forceinline__ u64 pack4(u16 a, u16 b, u16 c, u16 d) {
  return (u64)a | ((u64)b << 16) | ((u64)c << 32) | ((u64)d << 48);
}
__device__ __forceinline__ u64 umax64(u64 a, u64 b) { return a > b ? a : b; }
__device__ __forceinline__ void f16split(float x, u16& h, u16& l) {
  f16 hh = (f16)x;
  float r = x - (float)hh;
  f16 ll = (f16)r;
  h = *(u16*)&hh; l = *(u16*)&ll;
}
__device__ __forceinline__ u16 f16bits(float x) {
  f16 hh = (f16)x;
  return *(u16*)&hh;
}

// ---------------- weight transpose + fp16 split ([K][N] -> [N][K] planes) ----
struct TSrc { const float* p; int n0, w; };

__global__ __launch_bounds__(256) void wsplit(
    TSrc s0, TSrc s1, TSrc s2, TSrc s3, TSrc s4,
    int K, u16* __restrict__ Ph, u16* __restrict__ Pl) {
  __shared__ float tile[32][33];
  const int k0 = blockIdx.y * 32, n0 = blockIdx.x * 32;
  const int tid = threadIdx.x;
  const float* sp = nullptr; int off = 0, w = 0;
  if (s0.p && n0 >= s0.n0 && n0 < s0.n0 + s0.w) { sp = s0.p; off = s0.n0; w = s0.w; }
  else if (s1.p && n0 >= s1.n0 && n0 < s1.n0 + s1.w) { sp = s1.p; off = s1.n0; w = s1.w; }
  else if (s2.p && n0 >= s2.n0 && n0 < s2.n0 + s2.w) { sp = s2.p; off = s2.n0; w = s2.w; }
  else if (s3.p && n0 >= s3.n0 && n0 < s3.n0 + s3.w) { sp = s3.p; off = s3.n0; w = s3.w; }
  else if (s4.p && n0 >= s4.n0 && n0 < s4.n0 + s4.w) { sp = s4.p; off = s4.n0; w = s4.w; }
  {
    const int kl = tid >> 3, n4 = (tid & 7) * 4;
    float4 v = make_float4(0.f, 0.f, 0.f, 0.f);
    if (sp) v = *(const float4*)(sp + (size_t)(k0 + kl) * w + (n0 - off) + n4);
    tile[kl][n4 + 0] = v.x; tile[kl][n4 + 1] = v.y;
    tile[kl][n4 + 2] = v.z; tile[kl][n4 + 3] = v.w;
  }
  __syncthreads();
  const int nl = tid >> 3, k4 = (tid & 7) * 4;
  u16 h[4], lo[4];
#pragma unroll
  for (int j = 0; j < 4; ++j) f16split(tile[k4 + j][nl], h[j], lo[j]);
  const size_t o = (size_t)(n0 + nl) * K + k0 + k4;
  *(u64*)(Ph + o) = pack4(h[0], h[1], h[2], h[3]);
  *(u64*)(Pl + o) = pack4(lo[0], lo[1], lo[2], lo[3]);
}

// ---------------- x -> h/l fp16 planes (row-major) ---------------------------
__global__ __launch_bounds__(256) void xsplit(
    const float* __restrict__ x, u16* __restrict__ Xh, u16* __restrict__ Xl) {
  const int i = (blockIdx.x * 256 + threadIdx.x) * 4;
  float4 v = *(const float4*)(x + i);
  float e[4] = {v.x, v.y, v.z, v.w};
  u16 h[4], lo[4];
#pragma unroll
  for (int j = 0; j < 4; ++j) f16split(e[j], h[j], lo[j]);
  *(u64*)(Xh + i) = pack4(h[0], h[1], h[2], h[3]);
  *(u64*)(Xl + i) = pack4(lo[0], lo[1], lo[2], lo[3]);
}

// ---------------- fp16-split MFMA GEMM ---------------------------------------
// NPROD=1: C = Ah@Bh. NPROD=3: + Ah@Bl + Al@Bh.
// OUT: 0 = fp32 C; 1 = fp16 h-plane Ch;
//      2 = indexer epilogue (qi-> x2 planes rows bt*4+head, ki-> x2, kr fp32)
//      3 = I epilogue: I[t][s] = sum_j IW[j]*relu(acc_j)
struct GArg {
  const u16 *A0, *A1, *B0, *B1;
  float* C; u16* Ch;
  u16 *Qh, *Ql, *Kh, *Kl; float* KR; const float* IW;
  int lda, ldc, K, nbn;
};

template <int NPROD, int OUT>
__device__ __forceinline__ void gemm_body(const GArg& g, u16* Al, u16* Bl) {
  const int NS = (NPROD == 1) ? 1 : 2;
  const int tid = threadIdx.x;
  const int l = tid & 63, w = tid >> 6;
  const int wr = w >> 1, wc = w & 1;
  const int l15 = l & 15, l4 = l >> 4;
  const int bm = blockIdx.y * 128, bn = blockIdx.x * 128;
  const int ar2 = tid >> 1, akc = (tid & 1) * 16;
  const int brr = tid >> 2, bkc = (tid & 3) * 8;

  f32x4 acc[4][4];
#pragma unroll
  for (int i = 0; i < 4; ++i)
#pragma unroll
    for (int j = 0; j < 4; ++j) acc[i][j] = (f32x4){0.f, 0.f, 0.f, 0.f};

  for (int k0 = 0; k0 < g.K; k0 += 32) {
#pragma unroll
    for (int p = 0; p < NS; ++p) {
      const u16* Ap = (p == 0) ? g.A0 : g.A1;
      const size_t ab = (size_t)(bm + ar2) * g.lda + k0 + akc;
      *(uint4*)&Al[p * 5120 + ar2 * 40 + akc] = *(const uint4*)(Ap + ab);
      *(uint4*)&Al[p * 5120 + ar2 * 40 + akc + 8] = *(const uint4*)(Ap + ab + 8);
      const u16* Bp = (p == 0) ? g.B0 : g.B1;
#pragma unroll
      for (int i = 0; i < 2; ++i) {
        const int row = brr + i * 64;
        *(uint4*)&Bl[p * 5120 + row * 40 + bkc] =
            *(const uint4*)(Bp + (size_t)(bn + row) * g.K + k0 + bkc);
      }
    }
    __syncthreads();
    f16x8 af[NS == 1 ? 1 : 2][4], bf[NS == 1 ? 1 : 2][4];
#pragma unroll
    for (int f = 0; f < 4; ++f) {
      const int arow = wr * 64 + f * 16 + l15;
      const int brow = wc * 64 + f * 16 + l15;
#pragma unroll
      for (int p = 0; p < NS; ++p) {
        af[p][f] = *(const f16x8*)&Al[p * 5120 + arow * 40 + l4 * 8];
        bf[p][f] = *(const f16x8*)&Bl[p * 5120 + brow * 40 + l4 * 8];
      }
    }
#pragma unroll
    for (int fm = 0; fm < 4; ++fm)
#pragma unroll
      for (int fn = 0; fn < 4; ++fn) {
        f32x4 c = acc[fm][fn];
        c = mf16(af[0][fm], bf[0][fn], c);
        if (NPROD == 3) {
          c = mf16(af[0][fm], bf[1][fn], c);
          c = mf16(af[1][fm], bf[0][fn], c);
        }
        acc[fm][fn] = c;
      }
    __syncthreads();
  }
  if (OUT == 3) {
    const float w0 = g.IW[0], w1 = g.IW[1], w2 = g.IW[2], w3 = g.IW[3];
#pragma unroll
    for (int fm = 0; fm < 4; ++fm) {
      const int tt = (bm >> 2) + wr * 16 + fm * 4 + l4;
#pragma unroll
      for (int fn = 0; fn < 4; ++fn) {
        const int col = bn + wc * 64 + fn * 16 + l15;
        const f32x4 a = acc[fm][fn];
        float v = w0 * fmaxf(a[0], 0.f) + w1 * fmaxf(a[1], 0.f)
                + w2 * fmaxf(a[2], 0.f) + w3 * fmaxf(a[3], 0.f);
        g.C[(size_t)tt * g.ldc + col] = v;
      }
    }
    return;
  }
#pragma unroll
  for (int fm = 0; fm < 4; ++fm)
#pragma unroll
    for (int j = 0; j < 4; ++j) {
      const int row = bm + wr * 64 + fm * 16 + l4 * 4 + j;
#pragma unroll
      for (int fn = 0; fn < 4; ++fn) {
        const int col = bn + wc * 64 + fn * 16 + l15;
        const float val = acc[fm][fn][j];
        if (OUT == 0) {
          g.C[(size_t)row * g.ldc + col] = val;
        } else if (OUT == 1) {
          g.Ch[(size_t)row * g.ldc + col] = f16bits(val);
        } else {  // OUT == 2: local cols [qi 256 | ki 64 | kr 32 | pad 32]
          u16 hh, ll;
          f16split(val, hh, ll);
          if (col < 256) {
            const size_t o = ((size_t)row * 4 + (col >> 6)) * 64 + (col & 63);
            g.Qh[o] = hh; g.Ql[o] = ll;
          } else if (col < 320) {
            const size_t o = (size_t)row * 64 + (col - 256);
            g.Kh[o] = hh; g.Kl[o] = ll;
          } else if (col < 352) {
            g.KR[(size_t)row * 32 + (col - 320)] = val;
          }
        }
      }
    }
}

template <int NPROD, int OUT>
__global__ __launch_bounds__(256) void mfma_gemm(GArg g0, GArg g1) {
  __shared__ u16 Al[(NPROD == 1 ? 1 : 2) * 5120];
  __shared__ u16 Bl[(NPROD == 1 ? 1 : 2) * 5120];
  GArg g = (blockIdx.z == 0) ? g0 : g1;
  if ((int)blockIdx.x >= g.nbn) return;
  gemm_body<NPROD, OUT>(g, Al, Bl);
}

// G1a (fp16 single, h-plane out) and G1b (fp16 x2, indexer epilogue) fused.
__global__ __launch_bounds__(256) void g1_fused(GArg ga, GArg gb) {
  __shared__ u16 Al[2 * 5120];
  __shared__ u16 Bl[2 * 5120];
  if (blockIdx.z == 0) {
    if ((int)blockIdx.x >= ga.nbn) return;
    gemm_body<1, 1>(ga, Al, Bl);
  } else {
    if ((int)blockIdx.x >= gb.nbn) return;
    gemm_body<3, 2>(gb, Al, Bl);
  }
}

// ------------- TokenSelector top-k over precomputed I[b][t][s] ---------------
__global__ __launch_bounds__(256) void topk2(
    const float* __restrict__ IM, int* __restrict__ idx_sel) {
  const int wave = threadIdx.x >> 6, lane = threadIdx.x & 63;
  const int bt = blockIdx.x * 4 + wave;
  const int b = bt >> 10, t = bt & 1023;
  int* out = idx_sel + (size_t)bt * KTS;
  if (t < LWIN) {
    out[lane] = lane;
    if (lane < 32) out[64 + lane] = 64 + lane;
    return;
  }
  out[lane] = t - 63 + lane;
  const int nf = t - 63;
  const float* Irow = IM + ((size_t)b << 20) + ((size_t)t << 10);
  u64 key[16];
#pragma unroll
  for (int gq = 0; gq < 4; ++gq) {
    const int s0 = gq * 256 + lane * 4;
    float4 v = make_float4(0.f, 0.f, 0.f, 0.f);
    if (s0 < nf) v = *(const float4*)(Irow + s0);
    float e[4] = {v.x, v.y, v.z, v.w};
#pragma unroll
    for (int c = 0; c < 4; ++c) {
      u64 k = 0ull;
      const int s = s0 + c;
      if (s < nf) {
        unsigned ib = __float_as_uint(e[c]);
        if (ib == 0x80000000u) ib = 0u;
        ib = (ib & 0x80000000u) ? ~ib : (ib | 0x80000000u);
        k = ((u64)ib << 32) | (u64)(0xFFFFFFFFu - (unsigned)s);
      }
      key[gq * 4 + c] = k;
    }
  }
  u64 lm = key[0];
#pragma unroll
  for (int j = 1; j < 16; ++j) lm = umax64(lm, key[j]);
  const int topM = nf < 32 ? nf : 32;
  for (int it = 0; it < topM; ++it) {
    u64 m = lm;
#pragma unroll
    for (int off = 32; off > 0; off >>= 1) m = umax64(m, __shfl_xor(m, off));
    if (lane == 0)
      out[64 + it] = (int)(0xFFFFFFFFu - (unsigned)(m & 0xFFFFFFFFull));
    if (lm == m) {
#pragma unroll
      for (int j = 0; j < 16; ++j)
        if (key[j] == m) key[j] = 0ull;
      lm = key[0];
#pragma unroll
      for (int j = 1; j < 16; ++j) lm = umax64(lm, key[j]);
    }
  }
  if (lane < 32 - topM) out[64 + topM + lane] = t + 1 + lane;
}

// ----------------------- sparse attention per (b,t) --------------------------
// Lane-owned slots: lane l of head-group h computes full dots for k=l,l+32,l+64
// (K rows streamed as float4 from L2; zero per-k shuffles). Softmax once per
// head in registers. PV coalesced as before.
__global__ __launch_bounds__(256) void attn_kernel(
    const float* __restrict__ qproj, const float* __restrict__ kvproj,
    const float* __restrict__ krc, const int* __restrict__ idx_sel,
    const float* __restrict__ raw_delta, u16* __restrict__ aoh) {
  const int bt = ((blockIdx.x & 7) << 8) | (blockIdx.x >> 3);
  const int b = bt >> 10;
  const int t = bt & 1023;
  const int tid = threadIdx.x;

  __shared__ __align__(16) float qcs[NH * DH];    // 512
  __shared__ __align__(16) float qrs[NH * DR];    // 256
  __shared__ __align__(16) float krs[KTS * 36];   // stride 36 floats = 144B
  __shared__ float scS[NH * 100];
  __shared__ int selS[KTS];
  __shared__ int offS[KTS];
  __shared__ float thetav[16], deltav[16];
  __shared__ float mu[NH * DR];

  const float* qrow = qproj + (size_t)bt * NQP;
  qcs[tid] = qrow[tid];
  qcs[256 + tid] = qrow[256 + tid];
  mu[tid] = softplusf(qrow[512 + tid]);
  if (tid < KTS) {
    int s = idx_sel[(size_t)bt * KTS + tid];
    selS[tid] = s;
    offS[tid] = s * NKV;
  }
  if (tid < 16) {
    thetav[tid] = (float)(1.0 / pow(10000.0, (double)tid / 16.0));
    float r = raw_delta[tid];
    deltav[tid] = -6.2831853071795864769f * (1.f / (1.f + expf(-r)));
  }
  __syncthreads();

  if (tid < 128) {
    int h = tid >> 4, i = tid & 15;
    float ang = (float)t * thetav[i] + deltav[i];
    float c = cosf(ang), s = sinf(ang);
    float m1 = mu[h * DR + i], m2 = mu[h * DR + 16 + i];
    qrs[h * DR + i] = m1 * c - m2 * s;
    qrs[h * DR + 16 + i] = m1 * s + m2 * c;
  }
  const float* krb = krc + (size_t)b * L * 32;
  for (int e = tid; e < KTS * 16; e += 256) {
    int k = e >> 4, i = e & 15;
    int s = selS[k];
    float x1 = krb[(size_t)s * 32 + i];
    float x2 = krb[(size_t)s * 32 + 16 + i];
    float m1 = softplusf(x1), m2 = softplusf(x2);
    float ang = (float)k * thetav[i] + deltav[i];
    float c = cosf(ang), sn = sinf(ang);
    krs[k * 36 + i] = m1 * c - m2 * sn;
    krs[k * 36 + 16 + i] = m1 * sn + m2 * c;
  }
  __syncthreads();

  const float scale = 0.10206207261596575f;  // (64+32)^-0.5
  const int h = tid >> 5;
  const int l = tid & 31;
  const float* kvb = kvproj + (size_t)b * L * NKV;
  const float4* qc4 = (const float4*)&qcs[h * DH];
  float4 qr4[8];
#pragma unroll
  for (int i = 0; i < 8; ++i) qr4[i] = *(const float4*)&qrs[h * DR + 4 * i];

  float sc[3];
#pragma unroll
  for (int kk = 0; kk < 3; ++kk) {
    const int k = l + kk * 32;
    const float4* kp = (const float4*)(kvb + offS[k] + h * DH);
    float a0 = 0.f, a1 = 0.f;
#pragma unroll
    for (int d = 0; d < 16; d += 2) {
      float4 q0 = qc4[d], k0 = kp[d];
      float4 q1 = qc4[d + 1], k1 = kp[d + 1];
      a0 += q0.x * k0.x + q0.y * k0.y + q0.z * k0.z + q0.w * k0.w;
      a1 += q1.x * k1.x + q1.y * k1.y + q1.z * k1.z + q1.w * k1.w;
    }
    const float4* krp = (const float4*)&krs[k * 36];
#pragma unroll
    for (int i = 0; i < 8; ++i) {
      float4 kr = krp[i];
      a0 += qr4[i].x * kr.x + qr4[i].y * kr.y + qr4[i].z * kr.z + qr4[i].w * kr.w;
    }
    sc[kk] = (a0 + a1) * scale;
  }

  // softmax over 96 = 3 regs x 32 lanes
  float mx = fmaxf(fmaxf(sc[0], sc[1]), sc[2]);
#pragma unroll
  for (int off = 16; off > 0; off >>= 1) mx = fmaxf(mx, __shfl_xor(mx, off, 32));
  float e0 = expf(sc[0] - mx), e1 = expf(sc[1] - mx), e2 = expf(sc[2] - mx);
  float sum = e0 + e1 + e2;
#pragma unroll
  for (int off = 16; off > 0; off >>= 1) sum += __shfl_xor(sum, off, 32);
  float inv = 1.f / sum;
  scS[h * 100 + l] = e0 * inv;
  scS[h * 100 + l + 32] = e1 * inv;
  scS[h * 100 + l + 64] = e2 * inv;
  __syncthreads();

  float2 acc = make_float2(0.f, 0.f);
#pragma unroll 4
  for (int k = 0; k < KTS; ++k) {
    const float2 v = *(const float2*)(kvb + offS[k] + 512 + 2 * tid);
    const float w = scS[h * 100 + k];
    acc.x += w * v.x;
    acc.y += w * v.y;
  }
  const size_t o = (size_t)bt * 512 + 2 * tid;
  *(u32*)(aoh + o) = (u32)f16bits(acc.x) | ((u32)f16bits(acc.y) << 16);
}

// -----------------------------------------------------------------------------
extern "C" void kernel_launch(void* const* d_in, const int* in_sizes, int n_in,
                              void* d_out, int out_size, void* d_ws, size_t ws_size,
                              hipStream_t stream) {
  const float* x      = (const float*)d_in[0];
  const float* W_dkv  = (const float*)d_in[1];
  const float* W_uk   = (const float*)d_in[2];
  const float* W_uv   = (const float*)d_in[3];
  const float* W_dq   = (const float*)d_in[4];
  const float* W_uq   = (const float*)d_in[5];
  const float* W_qr   = (const float*)d_in[6];
  const float* W_kr   = (const float*)d_in[7];
  const float* W_out  = (const float*)d_in[8];
  const float* idx_wq = (const float*)d_in[9];
  const float* idx_wk = (const float*)d_in[10];
  const float* idx_w  = (const float*)d_in[11];
  const float* raw_dl = (const float*)d_in[12];
  float* out = (float*)d_out;

  const int M = 2 * L;  // 2048
  // ---- workspace ----
  u16* BxT_h  = (u16*)d_ws;                       // 1152*1024 x2
  u16* BxT_l  = BxT_h + 1152 * 1024;
  u16* BkvT_h = BxT_l + 1152 * 1024;              // 1024*256 x2
  u16* BkvT_l = BkvT_h + 1024 * 256;
  u16* BqT_h  = BkvT_l + 1024 * 256;              // 768*512 x2
  u16* BqT_l  = BqT_h + 768 * 512;
  u16* WoT_h  = BqT_l + 768 * 512;                // 1024*512 x2
  u16* WoT_l  = WoT_h + 1024 * 512;
  u16* Xh     = WoT_l + 1024 * 512;               // 2048*1024 x2 (dead after G1)
  u16* Xl     = Xh + (size_t)M * 1024;
  u16* XPh    = Xl + (size_t)M * 1024;            // 2048*768
  u16* AOh    = XPh + (size_t)M * 768;            // 2048*512
  u16* Qih    = AOh + (size_t)M * 512;            // 8192*64 x2 (rows bt*4+h)
  u16* Qil    = Qih + (size_t)M * 4 * 64;
  u16* Kih    = Qil + (size_t)M * 4 * 64;         // 2048*64 x2
  u16* Kil    = Kih + (size_t)M * 64;
  float* krc    = (float*)(Kil + (size_t)M * 64); // 2048*32
  float* kvproj = krc + (size_t)M * 32;           // 2048*1024
  float* qproj  = kvproj + (size_t)M * NKV;       // 2048*768
  int* sel      = (int*)(qproj + (size_t)M * NQP);
  float* IM     = (float*)Xh;                     // 2*1024*1024 f32 (aliases X)

  dim3 blk(256);
  TSrc z = {nullptr, 0, 0};
  GArg Z = {};
  // ---- weight prep ----
  {
    TSrc a = {W_dkv, 0, 256}, bq = {W_dq, 256, 512}, c = {idx_wq, 768, 256},
         d = {idx_wk, 1024, 64}, e = {W_kr, 1088, 32};
    hipLaunchKernelGGL(wsplit, dim3(1152 / 32, 1024 / 32), blk, 0, stream,
                       a, bq, c, d, e, 1024, BxT_h, BxT_l);
  }
  {
    TSrc a = {W_uk, 0, 512}, bq = {W_uv, 512, 512};
    hipLaunchKernelGGL(wsplit, dim3(1024 / 32, 256 / 32), blk, 0, stream,
                       a, bq, z, z, z, 256, BkvT_h, BkvT_l);
  }
  {
    TSrc a = {W_uq, 0, 512}, bq = {W_qr, 512, 256};
    hipLaunchKernelGGL(wsplit, dim3(768 / 32, 512 / 32), blk, 0, stream,
                       a, bq, z, z, z, 512, BqT_h, BqT_l);
  }
  {
    TSrc a = {W_out, 0, 1024};
    hipLaunchKernelGGL(wsplit, dim3(1024 / 32, 512 / 32), blk, 0, stream,
                       a, z, z, z, z, 512, WoT_h, WoT_l);
  }
  hipLaunchKernelGGL(xsplit, dim3(M * 1024 / (256 * 4)), blk, 0, stream,
                     x, Xh, Xl);
  // ---- G1 fused: z=0 cols 0..768 (c_kv|c_q); z=1 cols 768..1152 (indexer) ----
  {
    GArg ga = Z;
    ga.A0 = Xh; ga.B0 = BxT_h;
    ga.Ch = XPh; ga.lda = 1024; ga.ldc = 768; ga.K = 1024; ga.nbn = 6;
    GArg gb = Z;
    gb.A0 = Xh; gb.A1 = Xl;
    gb.B0 = BxT_h + 768 * 1024; gb.B1 = BxT_l + 768 * 1024;
    gb.Qh = Qih; gb.Ql = Qil; gb.Kh = Kih; gb.Kl = Kil; gb.KR = krc;
    gb.lda = 1024; gb.ldc = 0; gb.K = 1024; gb.nbn = 3;
    hipLaunchKernelGGL(g1_fused, dim3(6, M / 128, 2), blk, 0, stream, ga, gb);
  }
  // ---- I-GEMM: I[b][t][s] = sum_h w_h relu(qi_h(t).ki(s)), per-b via z ----
  {
    GArg g0 = Z, g1 = Z;
    g0.A0 = Qih; g0.A1 = Qil; g0.B0 = Kih; g0.B1 = Kil;
    g0.C = IM; g0.IW = idx_w;
    g0.lda = 64; g0.ldc = 1024; g0.K = 64; g0.nbn = 8;
    g1 = g0;
    g1.A0 = Qih + 4096 * 64; g1.A1 = Qil + 4096 * 64;
    g1.B0 = Kih + 1024 * 64; g1.B1 = Kil + 1024 * 64;
    g1.C = IM + 1024 * 1024;
    hipLaunchKernelGGL((mfma_gemm<3, 3>), dim3(8, 32, 2), blk, 0, stream,
                       g0, g1);
  }
  hipLaunchKernelGGL(topk2, dim3(M / 4), blk, 0, stream, IM, sel);
  // ---- G2 (kvproj, K=256) + G3 (qproj, K=512), fp16 single, fused via z ----
  {
    GArg g2 = Z, g3 = Z;
    g2.A0 = XPh; g2.B0 = BkvT_h;
    g2.C = kvproj; g2.lda = 768; g2.ldc = 1024; g2.K = 256; g2.nbn = 8;
    g3.A0 = XPh + 256; g3.B0 = BqT_h;
    g3.C = qproj; g3.lda = 768; g3.ldc = 768; g3.K = 512; g3.nbn = 6;
    hipLaunchKernelGGL((mfma_gemm<1, 0>), dim3(8, M / 128, 2), blk, 0, stream,
                       g2, g3);
  }
  hipLaunchKernelGGL(attn_kernel, dim3(M), blk, 0, stream,
                     qproj, kvproj, krc, sel, raw_dl, AOh);
  // ---- G5: out = ao @ W_out, fp16 single ----
  {
    GArg g = Z;
    g.A0 = AOh; g.B0 = WoT_h;
    g.C = out; g.lda = 512; g.ldc = 1024; g.K = 512; g.nbn = 8;
    hipLaunchKernelGGL((mfma_gemm<1, 0>), dim3(8, M / 128, 1), blk, 0, stream,
                       g, g);
  }
}

// Round 11
// 283.757 us; speedup vs baseline: 1.1490x; 1.1490x over previous
//
#include <hip/hip_runtime.h>
#include <math.h>

typedef unsigned short u16;
typedef unsigned int u32;
typedef unsigned long long u64;
typedef _Float16 f16;
typedef __attribute__((ext_vector_type(8))) _Float16 f16x8;
typedef __attribute__((ext_vector_type(4))) float f32x4;

#define L      1024
#define NH     8
#define DH     64
#define DR     32
#define KTS    96
#define LWIN   64
#define NKV    1024   // [kc 512 | vc 512]
#define NQP    768    // [qc 512 | qrp 256]

__device__ __forceinline__ float softplusf(float x) {
  return fmaxf(x, 0.f) + log1pf(expf(-fabsf(x)));
}
__device__ __forceinline__ f32x4 mf16(f16x8 a, f16x8 b, f32x4 c) {
  return __builtin_amdgcn_mfma_f32_16x16x32_f16(a, b, c, 0, 0, 0);
}
__device__ __forceinline__ u64 pack4(u16 a, u16 b, u16 c, u16 d) {
  return (u64)a | ((u64)b << 16) | ((u64)c << 32) | ((u64)d << 48);
}
__device__ __forceinline__ u64 umax64(u64 a, u64 b) { return a > b ? a : b; }
__device__ __forceinline__ void f16split(float x, u16& h, u16& l) {
  f16 hh = (f16)x;
  float r = x - (float)hh;
  f16 ll = (f16)r;
  h = *(u16*)&hh; l = *(u16*)&ll;
}
__device__ __forceinline__ u16 f16bits(float x) {
  f16 hh = (f16)x;
  return *(u16*)&hh;
}

// ---------------- weight transpose + fp16 split ([K][N] -> [N][K] planes) ----
struct TSrc { const float* p; int n0, w; };
struct WJob { TSrc s0, s1, s2, s3, s4; int K; u16 *Ph, *Pl; int nbx, nby; };

__global__ __launch_bounds__(256) void wsplit4(WJob j0, WJob j1, WJob j2,
                                               WJob j3) {
  __shared__ float tile[32][33];
  WJob j = (blockIdx.z == 0) ? j0
         : (blockIdx.z == 1) ? j1
         : (blockIdx.z == 2) ? j2 : j3;
  if ((int)blockIdx.x >= j.nbx || (int)blockIdx.y >= j.nby) return;
  const int k0 = blockIdx.y * 32, n0 = blockIdx.x * 32;
  const int tid = threadIdx.x;
  const float* sp = nullptr; int off = 0, w = 0;
  if (j.s0.p && n0 >= j.s0.n0 && n0 < j.s0.n0 + j.s0.w) { sp = j.s0.p; off = j.s0.n0; w = j.s0.w; }
  else if (j.s1.p && n0 >= j.s1.n0 && n0 < j.s1.n0 + j.s1.w) { sp = j.s1.p; off = j.s1.n0; w = j.s1.w; }
  else if (j.s2.p && n0 >= j.s2.n0 && n0 < j.s2.n0 + j.s2.w) { sp = j.s2.p; off = j.s2.n0; w = j.s2.w; }
  else if (j.s3.p && n0 >= j.s3.n0 && n0 < j.s3.n0 + j.s3.w) { sp = j.s3.p; off = j.s3.n0; w = j.s3.w; }
  else if (j.s4.p && n0 >= j.s4.n0 && n0 < j.s4.n0 + j.s4.w) { sp = j.s4.p; off = j.s4.n0; w = j.s4.w; }
  {
    const int kl = tid >> 3, n4 = (tid & 7) * 4;
    float4 v = make_float4(0.f, 0.f, 0.f, 0.f);
    if (sp) v = *(const float4*)(sp + (size_t)(k0 + kl) * w + (n0 - off) + n4);
    tile[kl][n4 + 0] = v.x; tile[kl][n4 + 1] = v.y;
    tile[kl][n4 + 2] = v.z; tile[kl][n4 + 3] = v.w;
  }
  __syncthreads();
  const int nl = tid >> 3, k4 = (tid & 7) * 4;
  u16 h[4], lo[4];
#pragma unroll
  for (int q = 0; q < 4; ++q) f16split(tile[k4 + q][nl], h[q], lo[q]);
  const size_t o = (size_t)(n0 + nl) * j.K + k0 + k4;
  *(u64*)(j.Ph + o) = pack4(h[0], h[1], h[2], h[3]);
  *(u64*)(j.Pl + o) = pack4(lo[0], lo[1], lo[2], lo[3]);
}

// ---------------- x -> h/l fp16 planes (row-major) ---------------------------
__global__ __launch_bounds__(256) void xsplit(
    const float* __restrict__ x, u16* __restrict__ Xh, u16* __restrict__ Xl) {
  const int i = (blockIdx.x * 256 + threadIdx.x) * 4;
  float4 v = *(const float4*)(x + i);
  float e[4] = {v.x, v.y, v.z, v.w};
  u16 h[4], lo[4];
#pragma unroll
  for (int j = 0; j < 4; ++j) f16split(e[j], h[j], lo[j]);
  *(u64*)(Xh + i) = pack4(h[0], h[1], h[2], h[3]);
  *(u64*)(Xl + i) = pack4(lo[0], lo[1], lo[2], lo[3]);
}

// ---------------- fp16-split MFMA GEMM ---------------------------------------
// NPROD=1: C = Ah@Bh. NPROD=3: + Ah@Bl + Al@Bh.
// OUT: 0 = fp32 C; 1 = fp16 h-plane Ch;
//      2 = indexer epilogue (qi-> x2 planes rows bt*4+head, ki-> x2, kr fp32)
//      3 = I epilogue: I[t][s] = sum_j IW[j]*relu(acc_j)
struct GArg {
  const u16 *A0, *A1, *B0, *B1;
  float* C; u16* Ch;
  u16 *Qh, *Ql, *Kh, *Kl; float* KR; const float* IW;
  int lda, ldc, K, nbn;
};

template <int NPROD, int OUT>
__device__ __forceinline__ void gemm_body(const GArg& g, u16* Al, u16* Bl) {
  const int NS = (NPROD == 1) ? 1 : 2;
  const int tid = threadIdx.x;
  const int l = tid & 63, w = tid >> 6;
  const int wr = w >> 1, wc = w & 1;
  const int l15 = l & 15, l4 = l >> 4;
  const int bm = blockIdx.y * 128, bn = blockIdx.x * 128;
  const int ar2 = tid >> 1, akc = (tid & 1) * 16;
  const int brr = tid >> 2, bkc = (tid & 3) * 8;

  f32x4 acc[4][4];
#pragma unroll
  for (int i = 0; i < 4; ++i)
#pragma unroll
    for (int j = 0; j < 4; ++j) acc[i][j] = (f32x4){0.f, 0.f, 0.f, 0.f};

  for (int k0 = 0; k0 < g.K; k0 += 32) {
#pragma unroll
    for (int p = 0; p < NS; ++p) {
      const u16* Ap = (p == 0) ? g.A0 : g.A1;
      const size_t ab = (size_t)(bm + ar2) * g.lda + k0 + akc;
      *(uint4*)&Al[p * 5120 + ar2 * 40 + akc] = *(const uint4*)(Ap + ab);
      *(uint4*)&Al[p * 5120 + ar2 * 40 + akc + 8] = *(const uint4*)(Ap + ab + 8);
      const u16* Bp = (p == 0) ? g.B0 : g.B1;
#pragma unroll
      for (int i = 0; i < 2; ++i) {
        const int row = brr + i * 64;
        *(uint4*)&Bl[p * 5120 + row * 40 + bkc] =
            *(const uint4*)(Bp + (size_t)(bn + row) * g.K + k0 + bkc);
      }
    }
    __syncthreads();
    f16x8 af[NS == 1 ? 1 : 2][4], bf[NS == 1 ? 1 : 2][4];
#pragma unroll
    for (int f = 0; f < 4; ++f) {
      const int arow = wr * 64 + f * 16 + l15;
      const int brow = wc * 64 + f * 16 + l15;
#pragma unroll
      for (int p = 0; p < NS; ++p) {
        af[p][f] = *(const f16x8*)&Al[p * 5120 + arow * 40 + l4 * 8];
        bf[p][f] = *(const f16x8*)&Bl[p * 5120 + brow * 40 + l4 * 8];
      }
    }
#pragma unroll
    for (int fm = 0; fm < 4; ++fm)
#pragma unroll
      for (int fn = 0; fn < 4; ++fn) {
        f32x4 c = acc[fm][fn];
        c = mf16(af[0][fm], bf[0][fn], c);
        if (NPROD == 3) {
          c = mf16(af[0][fm], bf[1][fn], c);
          c = mf16(af[1][fm], bf[0][fn], c);
        }
        acc[fm][fn] = c;
      }
    __syncthreads();
  }
  if (OUT == 3) {
    const float w0 = g.IW[0], w1 = g.IW[1], w2 = g.IW[2], w3 = g.IW[3];
#pragma unroll
    for (int fm = 0; fm < 4; ++fm) {
      const int tt = (bm >> 2) + wr * 16 + fm * 4 + l4;
#pragma unroll
      for (int fn = 0; fn < 4; ++fn) {
        const int col = bn + wc * 64 + fn * 16 + l15;
        const f32x4 a = acc[fm][fn];
        float v = w0 * fmaxf(a[0], 0.f) + w1 * fmaxf(a[1], 0.f)
                + w2 * fmaxf(a[2], 0.f) + w3 * fmaxf(a[3], 0.f);
        g.C[(size_t)tt * g.ldc + col] = v;
      }
    }
    return;
  }
#pragma unroll
  for (int fm = 0; fm < 4; ++fm)
#pragma unroll
    for (int j = 0; j < 4; ++j) {
      const int row = bm + wr * 64 + fm * 16 + l4 * 4 + j;
#pragma unroll
      for (int fn = 0; fn < 4; ++fn) {
        const int col = bn + wc * 64 + fn * 16 + l15;
        const float val = acc[fm][fn][j];
        if (OUT == 0) {
          g.C[(size_t)row * g.ldc + col] = val;
        } else if (OUT == 1) {
          g.Ch[(size_t)row * g.ldc + col] = f16bits(val);
        } else {  // OUT == 2: local cols [qi 256 | ki 64 | kr 32 | pad 32]
          u16 hh, ll;
          f16split(val, hh, ll);
          if (col < 256) {
            const size_t o = ((size_t)row * 4 + (col >> 6)) * 64 + (col & 63);
            g.Qh[o] = hh; g.Ql[o] = ll;
          } else if (col < 320) {
            const size_t o = (size_t)row * 64 + (col - 256);
            g.Kh[o] = hh; g.Kl[o] = ll;
          } else if (col < 352) {
            g.KR[(size_t)row * 32 + (col - 320)] = val;
          }
        }
      }
    }
}

template <int NPROD, int OUT>
__global__ __launch_bounds__(256) void mfma_gemm(GArg g0, GArg g1) {
  __shared__ u16 Al[(NPROD == 1 ? 1 : 2) * 5120];
  __shared__ u16 Bl[(NPROD == 1 ? 1 : 2) * 5120];
  GArg g = (blockIdx.z == 0) ? g0 : g1;
  if ((int)blockIdx.x >= g.nbn) return;
  gemm_body<NPROD, OUT>(g, Al, Bl);
}

// G1a (fp16 single, h-plane out) and G1b (fp16 x2, indexer epilogue) fused.
__global__ __launch_bounds__(256) void g1_fused(GArg ga, GArg gb) {
  __shared__ u16 Al[2 * 5120];
  __shared__ u16 Bl[2 * 5120];
  if (blockIdx.z == 0) {
    if ((int)blockIdx.x >= ga.nbn) return;
    gemm_body<1, 1>(ga, Al, Bl);
  } else {
    if ((int)blockIdx.x >= gb.nbn) return;
    gemm_body<3, 2>(gb, Al, Bl);
  }
}

// I-GEMM (z=0,1: per-batch, OUT=3) + G2 kvproj (z=2) + G3 qproj (z=3), fused
// for CU co-scheduling (all depend only on G1).
__global__ __launch_bounds__(256) void mid_fused(GArg gi0, GArg gi1, GArg g2,
                                                GArg g3) {
  __shared__ u16 Al[2 * 5120];
  __shared__ u16 Bl[2 * 5120];
  const int z = blockIdx.z;
  if (z < 2) {
    const GArg& g = z ? gi1 : gi0;
    if ((int)blockIdx.x >= g.nbn) return;
    gemm_body<3, 3>(g, Al, Bl);
  } else {
    const GArg& g = (z == 2) ? g2 : g3;
    if ((int)blockIdx.x >= g.nbn || (int)blockIdx.y >= 16) return;
    gemm_body<1, 0>(g, Al, Bl);
  }
}

// ------------- TokenSelector top-k over precomputed I[b][t][s] ---------------
__global__ __launch_bounds__(256) void topk2(
    const float* __restrict__ IM, int* __restrict__ idx_sel) {
  const int wave = threadIdx.x >> 6, lane = threadIdx.x & 63;
  const int bt = blockIdx.x * 4 + wave;
  const int b = bt >> 10, t = bt & 1023;
  int* out = idx_sel + (size_t)bt * KTS;
  if (t < LWIN) {
    out[lane] = lane;
    if (lane < 32) out[64 + lane] = 64 + lane;
    return;
  }
  out[lane] = t - 63 + lane;
  const int nf = t - 63;
  const float* Irow = IM + ((size_t)b << 20) + ((size_t)t << 10);
  u64 key[16];
#pragma unroll
  for (int gq = 0; gq < 4; ++gq) {
    const int s0 = gq * 256 + lane * 4;
    float4 v = make_float4(0.f, 0.f, 0.f, 0.f);
    if (s0 < nf) v = *(const float4*)(Irow + s0);
    float e[4] = {v.x, v.y, v.z, v.w};
#pragma unroll
    for (int c = 0; c < 4; ++c) {
      u64 k = 0ull;
      const int s = s0 + c;
      if (s < nf) {
        unsigned ib = __float_as_uint(e[c]);
        if (ib == 0x80000000u) ib = 0u;
        ib = (ib & 0x80000000u) ? ~ib : (ib | 0x80000000u);
        k = ((u64)ib << 32) | (u64)(0xFFFFFFFFu - (unsigned)s);
      }
      key[gq * 4 + c] = k;
    }
  }
  u64 lm = key[0];
#pragma unroll
  for (int j = 1; j < 16; ++j) lm = umax64(lm, key[j]);
  const int topM = nf < 32 ? nf : 32;
  for (int it = 0; it < topM; ++it) {
    u64 m = lm;
#pragma unroll
    for (int off = 32; off > 0; off >>= 1) m = umax64(m, __shfl_xor(m, off));
    if (lane == 0)
      out[64 + it] = (int)(0xFFFFFFFFu - (unsigned)(m & 0xFFFFFFFFull));
    if (lm == m) {
#pragma unroll
      for (int j = 0; j < 16; ++j)
        if (key[j] == m) key[j] = 0ull;
      lm = key[0];
#pragma unroll
      for (int j = 1; j < 16; ++j) lm = umax64(lm, key[j]);
    }
  }
  if (lane < 32 - topM) out[64 + topM + lane] = t + 1 + lane;
}

// ----------------------- sparse attention per (b,t) --------------------------
// Round-8 proven structure: k-major cooperative (whole block spans one K/V row
// -> fully coalesced), 32-lane-group per head, shfl reduce. XCD-chunked bt
// swizzle keeps gathered rows L2-resident.
__global__ __launch_bounds__(256) void attn_kernel(
    const float* __restrict__ qproj, const float* __restrict__ kvproj,
    const float* __restrict__ krc, const int* __restrict__ idx_sel,
    const float* __restrict__ raw_delta, u16* __restrict__ aoh) {
  const int bt = ((blockIdx.x & 7) << 8) | (blockIdx.x >> 3);
  const int b = bt >> 10;
  const int t = bt & 1023;
  const int tid = threadIdx.x;

  __shared__ __align__(16) float qcs[NH * DH];
  __shared__ __align__(16) float qrs[NH * DR];
  __shared__ __align__(16) float krs[KTS * DR];
  __shared__ float scS[NH * 100];
  __shared__ int selS[KTS];
  __shared__ int offS[KTS];
  __shared__ float thetav[16], deltav[16];
  __shared__ float mu[NH * DR];

  const float* qrow = qproj + (size_t)bt * NQP;
  qcs[tid] = qrow[tid];
  qcs[256 + tid] = qrow[256 + tid];
  mu[tid] = softplusf(qrow[512 + tid]);
  if (tid < KTS) {
    int s = idx_sel[(size_t)bt * KTS + tid];
    selS[tid] = s;
    offS[tid] = s * NKV;
  }
  if (tid < 16) {
    thetav[tid] = (float)(1.0 / pow(10000.0, (double)tid / 16.0));
    float r = raw_delta[tid];
    deltav[tid] = -6.2831853071795864769f * (1.f / (1.f + expf(-r)));
  }
  __syncthreads();

  if (tid < 128) {
    int h = tid >> 4, i = tid & 15;
    float ang = (float)t * thetav[i] + deltav[i];
    float c = cosf(ang), s = sinf(ang);
    float m1 = mu[h * DR + i], m2 = mu[h * DR + 16 + i];
    qrs[h * DR + i] = m1 * c - m2 * s;
    qrs[h * DR + 16 + i] = m1 * s + m2 * c;
  }
  const float* krb = krc + (size_t)b * L * 32;
  for (int e = tid; e < KTS * 16; e += 256) {
    int k = e >> 4, i = e & 15;
    int s = selS[k];
    float x1 = krb[(size_t)s * 32 + i];
    float x2 = krb[(size_t)s * 32 + 16 + i];
    float m1 = softplusf(x1), m2 = softplusf(x2);
    float ang = (float)k * thetav[i] + deltav[i];
    float c = cosf(ang), sn = sinf(ang);
    krs[k * DR + i] = m1 * c - m2 * sn;
    krs[k * DR + 16 + i] = m1 * sn + m2 * c;
  }
  __syncthreads();

  const float scale = 0.10206207261596575f;  // (64+32)^-0.5
  const int h = tid >> 5;
  const int l = tid & 31;
  const float2 qv = *(const float2*)&qcs[h * DH + 2 * l];
  const float qr1 = qrs[h * DR + l];
  const float* kvb = kvproj + (size_t)b * L * NKV;
#pragma unroll 8
  for (int k = 0; k < KTS; ++k) {
    const float2 kv = *(const float2*)(kvb + offS[k] + 2 * tid);
    float p = qv.x * kv.x + qv.y * kv.y + qr1 * krs[k * DR + l];
#pragma unroll
    for (int off = 16; off > 0; off >>= 1) p += __shfl_xor(p, off, 32);
    if (l == 0) scS[h * 100 + k] = p * scale;
  }
  __syncthreads();

  {
    float s0 = scS[h * 100 + l], s1 = scS[h * 100 + l + 32],
          s2 = scS[h * 100 + l + 64];
    float mx = fmaxf(fmaxf(s0, s1), s2);
#pragma unroll
    for (int off = 16; off > 0; off >>= 1) mx = fmaxf(mx, __shfl_xor(mx, off, 32));
    float e0 = expf(s0 - mx), e1 = expf(s1 - mx), e2 = expf(s2 - mx);
    float sum = e0 + e1 + e2;
#pragma unroll
    for (int off = 16; off > 0; off >>= 1) sum += __shfl_xor(sum, off, 32);
    float inv = 1.f / sum;
    scS[h * 100 + l] = e0 * inv;
    scS[h * 100 + l + 32] = e1 * inv;
    scS[h * 100 + l + 64] = e2 * inv;
  }
  __syncthreads();

  float2 acc = make_float2(0.f, 0.f);
#pragma unroll 4
  for (int k = 0; k < KTS; ++k) {
    const float2 v = *(const float2*)(kvb + offS[k] + 512 + 2 * tid);
    const float w = scS[h * 100 + k];
    acc.x += w * v.x;
    acc.y += w * v.y;
  }
  const size_t o = (size_t)bt * 512 + 2 * tid;
  *(u32*)(aoh + o) = (u32)f16bits(acc.x) | ((u32)f16bits(acc.y) << 16);
}

// -----------------------------------------------------------------------------
extern "C" void kernel_launch(void* const* d_in, const int* in_sizes, int n_in,
                              void* d_out, int out_size, void* d_ws, size_t ws_size,
                              hipStream_t stream) {
  const float* x      = (const float*)d_in[0];
  const float* W_dkv  = (const float*)d_in[1];
  const float* W_uk   = (const float*)d_in[2];
  const float* W_uv   = (const float*)d_in[3];
  const float* W_dq   = (const float*)d_in[4];
  const float* W_uq   = (const float*)d_in[5];
  const float* W_qr   = (const float*)d_in[6];
  const float* W_kr   = (const float*)d_in[7];
  const float* W_out  = (const float*)d_in[8];
  const float* idx_wq = (const float*)d_in[9];
  const float* idx_wk = (const float*)d_in[10];
  const float* idx_w  = (const float*)d_in[11];
  const float* raw_dl = (const float*)d_in[12];
  float* out = (float*)d_out;

  const int M = 2 * L;  // 2048
  // ---- workspace ----
  u16* BxT_h  = (u16*)d_ws;                       // 1152*1024 x2
  u16* BxT_l  = BxT_h + 1152 * 1024;
  u16* BkvT_h = BxT_l + 1152 * 1024;              // 1024*256 x2
  u16* BkvT_l = BkvT_h + 1024 * 256;
  u16* BqT_h  = BkvT_l + 1024 * 256;              // 768*512 x2
  u16* BqT_l  = BqT_h + 768 * 512;
  u16* WoT_h  = BqT_l + 768 * 512;                // 1024*512 x2
  u16* WoT_l  = WoT_h + 1024 * 512;
  u16* Xh     = WoT_l + 1024 * 512;               // 2048*1024 x2 (dead after G1)
  u16* Xl     = Xh + (size_t)M * 1024;
  u16* XPh    = Xl + (size_t)M * 1024;            // 2048*768
  u16* AOh    = XPh + (size_t)M * 768;            // 2048*512
  u16* Qih    = AOh + (size_t)M * 512;            // 8192*64 x2 (rows bt*4+h)
  u16* Qil    = Qih + (size_t)M * 4 * 64;
  u16* Kih    = Qil + (size_t)M * 4 * 64;         // 2048*64 x2
  u16* Kil    = Kih + (size_t)M * 64;
  float* krc    = (float*)(Kil + (size_t)M * 64); // 2048*32
  float* kvproj = krc + (size_t)M * 32;           // 2048*1024
  float* qproj  = kvproj + (size_t)M * NKV;       // 2048*768
  int* sel      = (int*)(qproj + (size_t)M * NQP);
  float* IM     = (float*)Xh;                     // 2*1024*1024 f32 (aliases X)

  dim3 blk(256);
  TSrc z = {nullptr, 0, 0};
  GArg Z = {};
  // ---- weight prep: 4 jobs, one dispatch ----
  {
    WJob j0 = {{W_dkv, 0, 256}, {W_dq, 256, 512}, {idx_wq, 768, 256},
               {idx_wk, 1024, 64}, {W_kr, 1088, 32},
               1024, BxT_h, BxT_l, 36, 32};
    WJob j1 = {{W_uk, 0, 512}, {W_uv, 512, 512}, z, z, z,
               256, BkvT_h, BkvT_l, 32, 8};
    WJob j2 = {{W_uq, 0, 512}, {W_qr, 512, 256}, z, z, z,
               512, BqT_h, BqT_l, 24, 16};
    WJob j3 = {{W_out, 0, 1024}, z, z, z, z,
               512, WoT_h, WoT_l, 32, 16};
    hipLaunchKernelGGL(wsplit4, dim3(36, 32, 4), blk, 0, stream, j0, j1, j2, j3);
  }
  hipLaunchKernelGGL(xsplit, dim3(M * 1024 / (256 * 4)), blk, 0, stream,
                     x, Xh, Xl);
  // ---- G1 fused: z=0 cols 0..768 (c_kv|c_q); z=1 cols 768..1152 (indexer) ----
  {
    GArg ga = Z;
    ga.A0 = Xh; ga.B0 = BxT_h;
    ga.Ch = XPh; ga.lda = 1024; ga.ldc = 768; ga.K = 1024; ga.nbn = 6;
    GArg gb = Z;
    gb.A0 = Xh; gb.A1 = Xl;
    gb.B0 = BxT_h + 768 * 1024; gb.B1 = BxT_l + 768 * 1024;
    gb.Qh = Qih; gb.Ql = Qil; gb.Kh = Kih; gb.Kl = Kil; gb.KR = krc;
    gb.lda = 1024; gb.ldc = 0; gb.K = 1024; gb.nbn = 3;
    hipLaunchKernelGGL(g1_fused, dim3(6, M / 128, 2), blk, 0, stream, ga, gb);
  }
  // ---- mid: I-GEMM (b0,b1) + G2 kvproj + G3 qproj, one dispatch ----
  {
    GArg gi0 = Z, gi1 = Z, g2 = Z, g3 = Z;
    gi0.A0 = Qih; gi0.A1 = Qil; gi0.B0 = Kih; gi0.B1 = Kil;
    gi0.C = IM; gi0.IW = idx_w;
    gi0.lda = 64; gi0.ldc = 1024; gi0.K = 64; gi0.nbn = 8;
    gi1 = gi0;
    gi1.A0 = Qih + 4096 * 64; gi1.A1 = Qil + 4096 * 64;
    gi1.B0 = Kih + 1024 * 64; gi1.B1 = Kil + 1024 * 64;
    gi1.C = IM + 1024 * 1024;
    g2.A0 = XPh; g2.B0 = BkvT_h;
    g2.C = kvproj; g2.lda = 768; g2.ldc = 1024; g2.K = 256; g2.nbn = 8;
    g3.A0 = XPh + 256; g3.B0 = BqT_h;
    g3.C = qproj; g3.lda = 768; g3.ldc = 768; g3.K = 512; g3.nbn = 6;
    hipLaunchKernelGGL(mid_fused, dim3(8, 32, 4), blk, 0, stream,
                       gi0, gi1, g2, g3);
  }
  hipLaunchKernelGGL(topk2, dim3(M / 4), blk, 0, stream, IM, sel);
  hipLaunchKernelGGL(attn_kernel, dim3(M), blk, 0, stream,
                     qproj, kvproj, krc, sel, raw_dl, AOh);
  // ---- G5: out = ao @ W_out, fp16 single ----
  {
    GArg g = Z;
    g.A0 = AOh; g.B0 = WoT_h;
    g.C = out; g.lda = 512; g.ldc = 1024; g.K = 512; g.nbn = 8;
    hipLaunchKernelGGL((mfma_gemm<1, 0>), dim3(8, M / 128, 1), blk, 0, stream,
                       g, g);
  }
}

// Round 12
// 247.779 us; speedup vs baseline: 1.3159x; 1.1452x over previous
//
#include <hip/hip_runtime.h>
#include <math.h>

typedef unsigned short u16;
typedef unsigned int u32;
typedef unsigned long long u64;
typedef _Float16 f16;
typedef __attribute__((ext_vector_type(2))) _Float16 f16x2;
typedef __attribute__((ext_vector_type(8))) _Float16 f16x8;
typedef __attribute__((ext_vector_type(4))) float f32x4;

#define L      1024
#define NH     8
#define DH     64
#define DR     32
#define KTS    96
#define LWIN   64
#define NQP    768    // [qc 512 | qrp 256]

__device__ __forceinline__ float softplusf(float x) {
  return fmaxf(x, 0.f) + log1pf(expf(-fabsf(x)));
}
__device__ __forceinline__ f32x4 mf16(f16x8 a, f16x8 b, f32x4 c) {
  return __builtin_amdgcn_mfma_f32_16x16x32_f16(a, b, c, 0, 0, 0);
}
__device__ __forceinline__ u64 pack4(u16 a, u16 b, u16 c, u16 d) {
  return (u64)a | ((u64)b << 16) | ((u64)c << 32) | ((u64)d << 48);
}
__device__ __forceinline__ u64 umax64(u64 a, u64 b) { return a > b ? a : b; }
__device__ __forceinline__ void f16split(float x, u16& h, u16& l) {
  f16 hh = (f16)x;
  float r = x - (float)hh;
  f16 ll = (f16)r;
  h = *(u16*)&hh; l = *(u16*)&ll;
}
__device__ __forceinline__ u16 f16bits(float x) {
  f16 hh = (f16)x;
  return *(u16*)&hh;
}
__device__ __forceinline__ float fdot2u(u32 a, u32 b, float c) {
  union { u32 u; f16x2 h; } ua, ub;
  ua.u = a; ub.u = b;
  return __builtin_amdgcn_fdot2(ua.h, ub.h, c, false);
}

// ---------------- weight transpose + fp16 split ([K][N] -> [N][K] planes) ----
struct TSrc { const float* p; int n0, w; };
struct WJob { TSrc s0, s1, s2, s3, s4; int K; u16 *Ph, *Pl; int nbx, nby; };

__global__ __launch_bounds__(256) void wsplit4(WJob j0, WJob j1, WJob j2,
                                               WJob j3) {
  __shared__ float tile[32][33];
  WJob j = (blockIdx.z == 0) ? j0
         : (blockIdx.z == 1) ? j1
         : (blockIdx.z == 2) ? j2 : j3;
  if ((int)blockIdx.x >= j.nbx || (int)blockIdx.y >= j.nby) return;
  const int k0 = blockIdx.y * 32, n0 = blockIdx.x * 32;
  const int tid = threadIdx.x;
  const float* sp = nullptr; int off = 0, w = 0;
  if (j.s0.p && n0 >= j.s0.n0 && n0 < j.s0.n0 + j.s0.w) { sp = j.s0.p; off = j.s0.n0; w = j.s0.w; }
  else if (j.s1.p && n0 >= j.s1.n0 && n0 < j.s1.n0 + j.s1.w) { sp = j.s1.p; off = j.s1.n0; w = j.s1.w; }
  else if (j.s2.p && n0 >= j.s2.n0 && n0 < j.s2.n0 + j.s2.w) { sp = j.s2.p; off = j.s2.n0; w = j.s2.w; }
  else if (j.s3.p && n0 >= j.s3.n0 && n0 < j.s3.n0 + j.s3.w) { sp = j.s3.p; off = j.s3.n0; w = j.s3.w; }
  else if (j.s4.p && n0 >= j.s4.n0 && n0 < j.s4.n0 + j.s4.w) { sp = j.s4.p; off = j.s4.n0; w = j.s4.w; }
  {
    const int kl = tid >> 3, n4 = (tid & 7) * 4;
    float4 v = make_float4(0.f, 0.f, 0.f, 0.f);
    if (sp) v = *(const float4*)(sp + (size_t)(k0 + kl) * w + (n0 - off) + n4);
    tile[kl][n4 + 0] = v.x; tile[kl][n4 + 1] = v.y;
    tile[kl][n4 + 2] = v.z; tile[kl][n4 + 3] = v.w;
  }
  __syncthreads();
  const int nl = tid >> 3, k4 = (tid & 7) * 4;
  u16 h[4], lo[4];
#pragma unroll
  for (int q = 0; q < 4; ++q) f16split(tile[k4 + q][nl], h[q], lo[q]);
  const size_t o = (size_t)(n0 + nl) * j.K + k0 + k4;
  *(u64*)(j.Ph + o) = pack4(h[0], h[1], h[2], h[3]);
  *(u64*)(j.Pl + o) = pack4(lo[0], lo[1], lo[2], lo[3]);
}

// ---------------- x -> h/l fp16 planes (row-major) ---------------------------
__global__ __launch_bounds__(256) void xsplit(
    const float* __restrict__ x, u16* __restrict__ Xh, u16* __restrict__ Xl) {
  const int i = (blockIdx.x * 256 + threadIdx.x) * 4;
  float4 v = *(const float4*)(x + i);
  float e[4] = {v.x, v.y, v.z, v.w};
  u16 h[4], lo[4];
#pragma unroll
  for (int j = 0; j < 4; ++j) f16split(e[j], h[j], lo[j]);
  *(u64*)(Xh + i) = pack4(h[0], h[1], h[2], h[3]);
  *(u64*)(Xl + i) = pack4(lo[0], lo[1], lo[2], lo[3]);
}

// ---------------- fp16-split MFMA GEMM ---------------------------------------
// NPROD=1: C = Ah@Bh. NPROD=3: + Ah@Bl + Al@Bh.
// OUT: 0 = fp32 C; 1 = fp16 h-plane Ch;
//      2 = indexer epilogue (qi-> x2 planes rows bt*4+head, ki-> x2, kr fp32)
//      3 = I epilogue: I[t][s] = sum_j IW[j]*relu(acc_j)
//      4 = kv epilogue: col<512 -> fp16 kcf (Ch), col>=512 -> fp32 vc (C)
struct GArg {
  const u16 *A0, *A1, *B0, *B1;
  float* C; u16* Ch;
  u16 *Qh, *Ql, *Kh, *Kl; float* KR; const float* IW;
  int lda, ldc, K, nbn;
};

template <int NPROD, int OUT>
__device__ __forceinline__ void gemm_body(const GArg& g, u16* Al, u16* Bl) {
  const int NS = (NPROD == 1) ? 1 : 2;
  const int tid = threadIdx.x;
  const int l = tid & 63, w = tid >> 6;
  const int wr = w >> 1, wc = w & 1;
  const int l15 = l & 15, l4 = l >> 4;
  const int bm = blockIdx.y * 128, bn = blockIdx.x * 128;
  const int ar2 = tid >> 1, akc = (tid & 1) * 16;
  const int brr = tid >> 2, bkc = (tid & 3) * 8;

  f32x4 acc[4][4];
#pragma unroll
  for (int i = 0; i < 4; ++i)
#pragma unroll
    for (int j = 0; j < 4; ++j) acc[i][j] = (f32x4){0.f, 0.f, 0.f, 0.f};

  for (int k0 = 0; k0 < g.K; k0 += 32) {
#pragma unroll
    for (int p = 0; p < NS; ++p) {
      const u16* Ap = (p == 0) ? g.A0 : g.A1;
      const size_t ab = (size_t)(bm + ar2) * g.lda + k0 + akc;
      *(uint4*)&Al[p * 5120 + ar2 * 40 + akc] = *(const uint4*)(Ap + ab);
      *(uint4*)&Al[p * 5120 + ar2 * 40 + akc + 8] = *(const uint4*)(Ap + ab + 8);
      const u16* Bp = (p == 0) ? g.B0 : g.B1;
#pragma unroll
      for (int i = 0; i < 2; ++i) {
        const int row = brr + i * 64;
        *(uint4*)&Bl[p * 5120 + row * 40 + bkc] =
            *(const uint4*)(Bp + (size_t)(bn + row) * g.K + k0 + bkc);
      }
    }
    __syncthreads();
    f16x8 af[NS == 1 ? 1 : 2][4], bf[NS == 1 ? 1 : 2][4];
#pragma unroll
    for (int f = 0; f < 4; ++f) {
      const int arow = wr * 64 + f * 16 + l15;
      const int brow = wc * 64 + f * 16 + l15;
#pragma unroll
      for (int p = 0; p < NS; ++p) {
        af[p][f] = *(const f16x8*)&Al[p * 5120 + arow * 40 + l4 * 8];
        bf[p][f] = *(const f16x8*)&Bl[p * 5120 + brow * 40 + l4 * 8];
      }
    }
#pragma unroll
    for (int fm = 0; fm < 4; ++fm)
#pragma unroll
      for (int fn = 0; fn < 4; ++fn) {
        f32x4 c = acc[fm][fn];
        c = mf16(af[0][fm], bf[0][fn], c);
        if (NPROD == 3) {
          c = mf16(af[0][fm], bf[1][fn], c);
          c = mf16(af[1][fm], bf[0][fn], c);
        }
        acc[fm][fn] = c;
      }
    __syncthreads();
  }
  if (OUT == 3) {
    const float w0 = g.IW[0], w1 = g.IW[1], w2 = g.IW[2], w3 = g.IW[3];
#pragma unroll
    for (int fm = 0; fm < 4; ++fm) {
      const int tt = (bm >> 2) + wr * 16 + fm * 4 + l4;
#pragma unroll
      for (int fn = 0; fn < 4; ++fn) {
        const int col = bn + wc * 64 + fn * 16 + l15;
        const f32x4 a = acc[fm][fn];
        float v = w0 * fmaxf(a[0], 0.f) + w1 * fmaxf(a[1], 0.f)
                + w2 * fmaxf(a[2], 0.f) + w3 * fmaxf(a[3], 0.f);
        g.C[(size_t)tt * g.ldc + col] = v;
      }
    }
    return;
  }
#pragma unroll
  for (int fm = 0; fm < 4; ++fm)
#pragma unroll
    for (int j = 0; j < 4; ++j) {
      const int row = bm + wr * 64 + fm * 16 + l4 * 4 + j;
#pragma unroll
      for (int fn = 0; fn < 4; ++fn) {
        const int col = bn + wc * 64 + fn * 16 + l15;
        const float val = acc[fm][fn][j];
        if (OUT == 0) {
          g.C[(size_t)row * g.ldc + col] = val;
        } else if (OUT == 1) {
          g.Ch[(size_t)row * g.ldc + col] = f16bits(val);
        } else if (OUT == 4) {
          if (col < 512) g.Ch[(size_t)row * 512 + col] = f16bits(val);
          else g.C[(size_t)row * 512 + (col - 512)] = val;
        } else {  // OUT == 2: local cols [qi 256 | ki 64 | kr 32 | pad 32]
          u16 hh, ll;
          f16split(val, hh, ll);
          if (col < 256) {
            const size_t o = ((size_t)row * 4 + (col >> 6)) * 64 + (col & 63);
            g.Qh[o] = hh; g.Ql[o] = ll;
          } else if (col < 320) {
            const size_t o = (size_t)row * 64 + (col - 256);
            g.Kh[o] = hh; g.Kl[o] = ll;
          } else if (col < 352) {
            g.KR[(size_t)row * 32 + (col - 320)] = val;
          }
        }
      }
    }
}

template <int NPROD, int OUT>
__global__ __launch_bounds__(256) void mfma_gemm(GArg g0, GArg g1) {
  __shared__ u16 Al[(NPROD == 1 ? 1 : 2) * 5120];
  __shared__ u16 Bl[(NPROD == 1 ? 1 : 2) * 5120];
  GArg g = (blockIdx.z == 0) ? g0 : g1;
  if ((int)blockIdx.x >= g.nbn) return;
  gemm_body<NPROD, OUT>(g, Al, Bl);
}

// G1a (fp16 single, h-plane out) and G1b (fp16 x2, indexer epilogue) fused.
__global__ __launch_bounds__(256) void g1_fused(GArg ga, GArg gb) {
  __shared__ u16 Al[2 * 5120];
  __shared__ u16 Bl[2 * 5120];
  if (blockIdx.z == 0) {
    if ((int)blockIdx.x >= ga.nbn) return;
    gemm_body<1, 1>(ga, Al, Bl);
  } else {
    if ((int)blockIdx.x >= gb.nbn) return;
    gemm_body<3, 2>(gb, Al, Bl);
  }
}

// I-GEMM (z=0,1: per-batch, OUT=3) + G2 kv (z=2, OUT=4) + G3 qproj (z=3).
__global__ __launch_bounds__(256) void mid_fused(GArg gi0, GArg gi1, GArg g2,
                                                GArg g3) {
  __shared__ u16 Al[2 * 5120];
  __shared__ u16 Bl[2 * 5120];
  const int z = blockIdx.z;
  if (z < 2) {
    const GArg& g = z ? gi1 : gi0;
    if ((int)blockIdx.x >= g.nbn) return;
    gemm_body<3, 3>(g, Al, Bl);
  } else if (z == 2) {
    if ((int)blockIdx.x >= g2.nbn || (int)blockIdx.y >= 16) return;
    gemm_body<1, 4>(g2, Al, Bl);
  } else {
    if ((int)blockIdx.x >= g3.nbn || (int)blockIdx.y >= 16) return;
    gemm_body<1, 0>(g3, Al, Bl);
  }
}

// ------------- TokenSelector top-k over precomputed I[b][t][s] ---------------
__global__ __launch_bounds__(256) void topk2(
    const float* __restrict__ IM, int* __restrict__ idx_sel) {
  const int wave = threadIdx.x >> 6, lane = threadIdx.x & 63;
  const int bt = blockIdx.x * 4 + wave;
  const int b = bt >> 10, t = bt & 1023;
  int* out = idx_sel + (size_t)bt * KTS;
  if (t < LWIN) {
    out[lane] = lane;
    if (lane < 32) out[64 + lane] = 64 + lane;
    return;
  }
  out[lane] = t - 63 + lane;
  const int nf = t - 63;
  const float* Irow = IM + ((size_t)b << 20) + ((size_t)t << 10);
  u64 key[16];
#pragma unroll
  for (int gq = 0; gq < 4; ++gq) {
    const int s0 = gq * 256 + lane * 4;
    float4 v = make_float4(0.f, 0.f, 0.f, 0.f);
    if (s0 < nf) v = *(const float4*)(Irow + s0);
    float e[4] = {v.x, v.y, v.z, v.w};
#pragma unroll
    for (int c = 0; c < 4; ++c) {
      u64 k = 0ull;
      const int s = s0 + c;
      if (s < nf) {
        unsigned ib = __float_as_uint(e[c]);
        if (ib == 0x80000000u) ib = 0u;
        ib = (ib & 0x80000000u) ? ~ib : (ib | 0x80000000u);
        k = ((u64)ib << 32) | (u64)(0xFFFFFFFFu - (unsigned)s);
      }
      key[gq * 4 + c] = k;
    }
  }
  u64 lm = key[0];
#pragma unroll
  for (int j = 1; j < 16; ++j) lm = umax64(lm, key[j]);
  const int topM = nf < 32 ? nf : 32;
  for (int it = 0; it < topM; ++it) {
    u64 m = lm;
#pragma unroll
    for (int off = 32; off > 0; off >>= 1) m = umax64(m, __shfl_xor(m, off));
    if (lane == 0)
      out[64 + it] = (int)(0xFFFFFFFFu - (unsigned)(m & 0xFFFFFFFFull));
    if (lm == m) {
#pragma unroll
      for (int j = 0; j < 16; ++j)
        if (key[j] == m) key[j] = 0ull;
      lm = key[0];
#pragma unroll
      for (int j = 1; j < 16; ++j) lm = umax64(lm, key[j]);
    }
  }
  if (lane < 32 - topM) out[64 + topM + lane] = t + 1 + lane;
}

// ----------------------- sparse attention per (b,t) --------------------------
// k-major cooperative structure (round-8 proven) with:
//  - fp16 kc + v_dot2_f32_f16 for the content dot (1 instr / 2 dims)
//  - 4-slot folded wave reduction: 6 shfl per 4 slots (vs 20)
__global__ __launch_bounds__(256) void attn_kernel(
    const float* __restrict__ qproj, const u16* __restrict__ kcf,
    const float* __restrict__ vc, const float* __restrict__ krc,
    const int* __restrict__ idx_sel, const float* __restrict__ raw_delta,
    u16* __restrict__ aoh) {
  const int bt = ((blockIdx.x & 7) << 8) | (blockIdx.x >> 3);
  const int b = bt >> 10;
  const int t = bt & 1023;
  const int tid = threadIdx.x;

  __shared__ __align__(16) float qrs[NH * DR];
  __shared__ __align__(16) float krs[KTS * DR];
  __shared__ u32 qc2S[256];
  __shared__ float scS[NH * 100];
  __shared__ int selS[KTS];
  __shared__ int offS[KTS];
  __shared__ float thetav[16], deltav[16];
  __shared__ float mu[NH * DR];

  const float* qrow = qproj + (size_t)bt * NQP;
  {
    const int hh = tid >> 5, ll = tid & 31;
    float q0 = qrow[hh * 64 + 2 * ll], q1 = qrow[hh * 64 + 2 * ll + 1];
    qc2S[tid] = (u32)f16bits(q0) | ((u32)f16bits(q1) << 16);
  }
  mu[tid] = softplusf(qrow[512 + tid]);
  if (tid < KTS) {
    int s = idx_sel[(size_t)bt * KTS + tid];
    selS[tid] = s;
    offS[tid] = s * 512;
  }
  if (tid < 16) {
    thetav[tid] = (float)(1.0 / pow(10000.0, (double)tid / 16.0));
    float r = raw_delta[tid];
    deltav[tid] = -6.2831853071795864769f * (1.f / (1.f + expf(-r)));
  }
  __syncthreads();

  if (tid < 128) {
    int h = tid >> 4, i = tid & 15;
    float ang = (float)t * thetav[i] + deltav[i];
    float c = cosf(ang), s = sinf(ang);
    float m1 = mu[h * DR + i], m2 = mu[h * DR + 16 + i];
    qrs[h * DR + i] = m1 * c - m2 * s;
    qrs[h * DR + 16 + i] = m1 * s + m2 * c;
  }
  const float* krb = krc + (size_t)b * L * 32;
  for (int e = tid; e < KTS * 16; e += 256) {
    int k = e >> 4, i = e & 15;
    int s = selS[k];
    float x1 = krb[(size_t)s * 32 + i];
    float x2 = krb[(size_t)s * 32 + 16 + i];
    float m1 = softplusf(x1), m2 = softplusf(x2);
    float ang = (float)k * thetav[i] + deltav[i];
    float c = cosf(ang), sn = sinf(ang);
    krs[k * DR + i] = m1 * c - m2 * sn;
    krs[k * DR + 16 + i] = m1 * sn + m2 * c;
  }
  __syncthreads();

  const float scale = 0.10206207261596575f;  // (64+32)^-0.5
  const int h = tid >> 5;
  const int l = tid & 31;
  const u32 q2 = qc2S[tid];
  const float qr1 = qrs[h * DR + l];
  const u16* kcb = kcf + (size_t)b * L * 512 + h * 64 + 2 * l;
  const float* vcb = vc + (size_t)b * L * 512;

#pragma unroll 4
  for (int i = 0; i < KTS / 4; ++i) {
    const int kb = i * 4;
    u32 kv0 = *(const u32*)(kcb + offS[kb + 0]);
    u32 kv1 = *(const u32*)(kcb + offS[kb + 1]);
    u32 kv2 = *(const u32*)(kcb + offS[kb + 2]);
    u32 kv3 = *(const u32*)(kcb + offS[kb + 3]);
    float p0 = fdot2u(q2, kv0, qr1 * krs[(kb + 0) * DR + l]);
    float p1 = fdot2u(q2, kv1, qr1 * krs[(kb + 1) * DR + l]);
    float p2 = fdot2u(q2, kv2, qr1 * krs[(kb + 2) * DR + l]);
    float p3 = fdot2u(q2, kv3, qr1 * krs[(kb + 3) * DR + l]);
    // folded reduction: halves own {p0,p1}x{p2,p3}, quarters one each
    float a = ((l & 16) ? p1 : p0) + __shfl_xor((l & 16) ? p0 : p1, 16, 32);
    float bb = ((l & 16) ? p3 : p2) + __shfl_xor((l & 16) ? p2 : p3, 16, 32);
    float c = ((l & 8) ? bb : a) + __shfl_xor((l & 8) ? a : bb, 8, 32);
    c += __shfl_xor(c, 4, 32);
    c += __shfl_xor(c, 2, 32);
    c += __shfl_xor(c, 1, 32);
    // lanes 0/16/8/24 hold sums for kb+0/kb+1/kb+2/kb+3
    if ((l & 7) == 0)
      scS[h * 100 + kb + ((l >> 4) & 1) + ((l >> 3) & 1) * 2] = c * scale;
  }
  __syncthreads();

  {
    float s0 = scS[h * 100 + l], s1 = scS[h * 100 + l + 32],
          s2 = scS[h * 100 + l + 64];
    float mx = fmaxf(fmaxf(s0, s1), s2);
#pragma unroll
    for (int off = 16; off > 0; off >>= 1) mx = fmaxf(mx, __shfl_xor(mx, off, 32));
    float e0 = expf(s0 - mx), e1 = expf(s1 - mx), e2 = expf(s2 - mx);
    float sum = e0 + e1 + e2;
#pragma unroll
    for (int off = 16; off > 0; off >>= 1) sum += __shfl_xor(sum, off, 32);
    float inv = 1.f / sum;
    scS[h * 100 + l] = e0 * inv;
    scS[h * 100 + l + 32] = e1 * inv;
    scS[h * 100 + l + 64] = e2 * inv;
  }
  __syncthreads();

  float2 acc = make_float2(0.f, 0.f);
#pragma unroll 4
  for (int k = 0; k < KTS; ++k) {
    const float2 v = *(const float2*)(vcb + offS[k] + 2 * tid);
    const float w = scS[h * 100 + k];
    acc.x += w * v.x;
    acc.y += w * v.y;
  }
  const size_t o = (size_t)bt * 512 + 2 * tid;
  *(u32*)(aoh + o) = (u32)f16bits(acc.x) | ((u32)f16bits(acc.y) << 16);
}

// -----------------------------------------------------------------------------
extern "C" void kernel_launch(void* const* d_in, const int* in_sizes, int n_in,
                              void* d_out, int out_size, void* d_ws, size_t ws_size,
                              hipStream_t stream) {
  const float* x      = (const float*)d_in[0];
  const float* W_dkv  = (const float*)d_in[1];
  const float* W_uk   = (const float*)d_in[2];
  const float* W_uv   = (const float*)d_in[3];
  const float* W_dq   = (const float*)d_in[4];
  const float* W_uq   = (const float*)d_in[5];
  const float* W_qr   = (const float*)d_in[6];
  const float* W_kr   = (const float*)d_in[7];
  const float* W_out  = (const float*)d_in[8];
  const float* idx_wq = (const float*)d_in[9];
  const float* idx_wk = (const float*)d_in[10];
  const float* idx_w  = (const float*)d_in[11];
  const float* raw_dl = (const float*)d_in[12];
  float* out = (float*)d_out;

  const int M = 2 * L;  // 2048
  // ---- workspace ----
  u16* BxT_h  = (u16*)d_ws;                       // 1152*1024 x2
  u16* BxT_l  = BxT_h + 1152 * 1024;
  u16* BkvT_h = BxT_l + 1152 * 1024;              // 1024*256 x2
  u16* BkvT_l = BkvT_h + 1024 * 256;
  u16* BqT_h  = BkvT_l + 1024 * 256;              // 768*512 x2
  u16* BqT_l  = BqT_h + 768 * 512;
  u16* WoT_h  = BqT_l + 768 * 512;                // 1024*512 x2
  u16* WoT_l  = WoT_h + 1024 * 512;
  u16* Xh     = WoT_l + 1024 * 512;               // 2048*1024 x2 (dead after G1)
  u16* Xl     = Xh + (size_t)M * 1024;
  u16* XPh    = Xl + (size_t)M * 1024;            // 2048*768
  u16* AOh    = XPh + (size_t)M * 768;            // 2048*512
  u16* Qih    = AOh + (size_t)M * 512;            // 8192*64 x2 (rows bt*4+h)
  u16* Qil    = Qih + (size_t)M * 4 * 64;
  u16* Kih    = Qil + (size_t)M * 4 * 64;         // 2048*64 x2
  u16* Kil    = Kih + (size_t)M * 64;
  u16* kcf    = Kil + (size_t)M * 64;             // 2048*512 fp16 (kc)
  float* krc    = (float*)(kcf + (size_t)M * 512);// 2048*32
  float* vc     = krc + (size_t)M * 32;           // 2048*512 fp32 (vc)
  float* qproj  = vc + (size_t)M * 512;           // 2048*768
  int* sel      = (int*)(qproj + (size_t)M * NQP);
  float* IM     = (float*)Xh;                     // 2*1024*1024 f32 (aliases X)

  dim3 blk(256);
  TSrc z = {nullptr, 0, 0};
  GArg Z = {};
  // ---- weight prep: 4 jobs, one dispatch ----
  {
    WJob j0 = {{W_dkv, 0, 256}, {W_dq, 256, 512}, {idx_wq, 768, 256},
               {idx_wk, 1024, 64}, {W_kr, 1088, 32},
               1024, BxT_h, BxT_l, 36, 32};
    WJob j1 = {{W_uk, 0, 512}, {W_uv, 512, 512}, z, z, z,
               256, BkvT_h, BkvT_l, 32, 8};
    WJob j2 = {{W_uq, 0, 512}, {W_qr, 512, 256}, z, z, z,
               512, BqT_h, BqT_l, 24, 16};
    WJob j3 = {{W_out, 0, 1024}, z, z, z, z,
               512, WoT_h, WoT_l, 32, 16};
    hipLaunchKernelGGL(wsplit4, dim3(36, 32, 4), blk, 0, stream, j0, j1, j2, j3);
  }
  hipLaunchKernelGGL(xsplit, dim3(M * 1024 / (256 * 4)), blk, 0, stream,
                     x, Xh, Xl);
  // ---- G1 fused: z=0 cols 0..768 (c_kv|c_q); z=1 cols 768..1152 (indexer) ----
  {
    GArg ga = Z;
    ga.A0 = Xh; ga.B0 = BxT_h;
    ga.Ch = XPh; ga.lda = 1024; ga.ldc = 768; ga.K = 1024; ga.nbn = 6;
    GArg gb = Z;
    gb.A0 = Xh; gb.A1 = Xl;
    gb.B0 = BxT_h + 768 * 1024; gb.B1 = BxT_l + 768 * 1024;
    gb.Qh = Qih; gb.Ql = Qil; gb.Kh = Kih; gb.Kl = Kil; gb.KR = krc;
    gb.lda = 1024; gb.ldc = 0; gb.K = 1024; gb.nbn = 3;
    hipLaunchKernelGGL(g1_fused, dim3(6, M / 128, 2), blk, 0, stream, ga, gb);
  }
  // ---- mid: I-GEMM (b0,b1) + G2 kv (fp16 kc + fp32 vc) + G3 qproj ----
  {
    GArg gi0 = Z, gi1 = Z, g2 = Z, g3 = Z;
    gi0.A0 = Qih; gi0.A1 = Qil; gi0.B0 = Kih; gi0.B1 = Kil;
    gi0.C = IM; gi0.IW = idx_w;
    gi0.lda = 64; gi0.ldc = 1024; gi0.K = 64; gi0.nbn = 8;
    gi1 = gi0;
    gi1.A0 = Qih + 4096 * 64; gi1.A1 = Qil + 4096 * 64;
    gi1.B0 = Kih + 1024 * 64; gi1.B1 = Kil + 1024 * 64;
    gi1.C = IM + 1024 * 1024;
    g2.A0 = XPh; g2.B0 = BkvT_h;
    g2.C = vc; g2.Ch = kcf; g2.lda = 768; g2.ldc = 512; g2.K = 256; g2.nbn = 8;
    g3.A0 = XPh + 256; g3.B0 = BqT_h;
    g3.C = qproj; g3.lda = 768; g3.ldc = 768; g3.K = 512; g3.nbn = 6;
    hipLaunchKernelGGL(mid_fused, dim3(8, 32, 4), blk, 0, stream,
                       gi0, gi1, g2, g3);
  }
  hipLaunchKernelGGL(topk2, dim3(M / 4), blk, 0, stream, IM, sel);
  hipLaunchKernelGGL(attn_kernel, dim3(M), blk, 0, stream,
                     qproj, kcf, vc, krc, sel, raw_dl, AOh);
  // ---- G5: out = ao @ W_out, fp16 single ----
  {
    GArg g = Z;
    g.A0 = AOh; g.B0 = WoT_h;
    g.C = out; g.lda = 512; g.ldc = 1024; g.K = 512; g.nbn = 8;
    hipLaunchKernelGGL((mfma_gemm<1, 0>), dim3(8, M / 128, 1), blk, 0, stream,
                       g, g);
  }
}